// Round 7
// baseline (290.026 us; speedup 1.0000x reference)
//
#include <hip/hip_runtime.h>
#include <hip/hip_cooperative_groups.h>
namespace cg = cooperative_groups;

#define BB 16384
#define KK 64
#define DD 128
#define SEG 128
#define NBLK 256

// ---------------------------------------------------------------------------
// Single cooperative kernel, 4 phases separated by grid.sync():
//  A: per-64-row tiled GEMM -> log_resp, per-block cluster histogram
//  B: redundant prefix-sums from bhist (coalesced), parallel scatter to sorted
//  C: per-item (<=128 rows) Sxx partial, non-atomic to part[b]; emp atomics
//  D: per (cluster, quarter) streaming reduce of partials -> 2 scalars
// ---------------------------------------------------------------------------
__global__ __launch_bounds__(256) void k_fused(
    const float* __restrict__ x, const float* __restrict__ centers,
    float* __restrict__ log_resp, float* __restrict__ outscalars,
    int* __restrict__ sorted, int* __restrict__ bhist,
    float* __restrict__ part, float* __restrict__ emp)
{
    cg::grid_group grid = cg::this_grid();

    __shared__ __align__(16) char smem[67584];
    float (*xs)[132]   = (float(*)[132])smem;           // phase A: 33792 B
    float (*ct)[66]    = (float(*)[66])(smem + 33792);  // phase A: 33792 B
    int*   rows_s      = (int*)smem;                    // phase C: 512 B
    float (*xr_s)[DD]  = (float(*)[DD])(smem + 512);    // phase C: 4 KB
    float (*red)[4096] = (float(*)[4096])smem;          // phase D: 64 KB

    __shared__ float cn2[KK];
    __shared__ int   lh[KK];            // A: histogram, B: scatter cursor
    __shared__ int   a_s[64];           // A->B: this block's 64 assignments
    __shared__ int   ph_tot[4][KK], ph_pre[4][KK];
    __shared__ int   m_cnt[KK], m_base[KK], m_pre[KK], m_ist[KK], m_ien[KK];
    __shared__ int   m_item[2];         // this block's (k, seg), k=-1 if none
    __shared__ float mu_s[DD], emp_s[DD];
    __shared__ float rds[4], ros[4], rmm[4];

    const int tid = threadIdx.x;
    const int b   = blockIdx.x;

    // ---------------- Phase A ----------------
    if (b == 0 && tid < 2) outscalars[tid] = 0.f;
    if (tid < 32) emp[b * 32 + tid] = 0.f;            // 256*32 = 8192
    if (tid < KK) lh[tid] = 0;

    const int row0 = b * 64;
    for (int g = tid; g < 64 * 32; g += 256) {
        int r = g >> 5, c4 = g & 31;
        float4 v = ((const float4*)(x + (size_t)(row0 + r) * DD))[c4];
        *(float4*)&xs[r][c4 * 4] = v;
    }
    for (int g = tid; g < KK * 32; g += 256) {
        int k = g >> 5, c4 = g & 31;
        float4 v = ((const float4*)(centers + (size_t)k * DD))[c4];
        ct[c4 * 4 + 0][k] = v.x;
        ct[c4 * 4 + 1][k] = v.y;
        ct[c4 * 4 + 2][k] = v.z;
        ct[c4 * 4 + 3][k] = v.w;
    }
    __syncthreads();
    if (tid < KK) {
        float s = 0.f;
        for (int d = 0; d < DD; ++d) { float c = ct[d][tid]; s = fmaf(c, c, s); }
        cn2[tid] = s;
    }
    __syncthreads();

    {
        const int tr = tid >> 5;
        const int tc = tid & 31;
        const int k0 = tc * 2, k1 = k0 + 1;

        float acc0[8], acc1[8];
        #pragma unroll
        for (int i = 0; i < 8; ++i) { acc0[i] = 0.f; acc1[i] = 0.f; }

        for (int d = 0; d < DD; d += 4) {
            float2 b0 = *(const float2*)&ct[d + 0][k0];
            float2 b1 = *(const float2*)&ct[d + 1][k0];
            float2 b2 = *(const float2*)&ct[d + 2][k0];
            float2 b3 = *(const float2*)&ct[d + 3][k0];
            #pragma unroll
            for (int i = 0; i < 8; ++i) {
                float4 a = *(const float4*)&xs[tr * 8 + i][d];
                acc0[i] = fmaf(a.x, b0.x, acc0[i]);
                acc1[i] = fmaf(a.x, b0.y, acc1[i]);
                acc0[i] = fmaf(a.y, b1.x, acc0[i]);
                acc1[i] = fmaf(a.y, b1.y, acc1[i]);
                acc0[i] = fmaf(a.z, b2.x, acc0[i]);
                acc1[i] = fmaf(a.z, b2.y, acc1[i]);
                acc0[i] = fmaf(a.w, b3.x, acc0[i]);
                acc1[i] = fmaf(a.w, b3.y, acc1[i]);
            }
        }

        const float cn0 = 0.5f * cn2[k0], cn1 = 0.5f * cn2[k1];
        #pragma unroll
        for (int i = 0; i < 8; ++i) {
            int row = row0 + tr * 8 + i;
            float v0 = acc0[i] - cn0;
            float v1 = acc1[i] - cn1;
            float m; int idx;
            if (v1 > v0) { m = v1; idx = k1; } else { m = v0; idx = k0; }
            #pragma unroll
            for (int off = 1; off < 32; off <<= 1) {
                float ov = __shfl_xor(m, off);
                int   oi = __shfl_xor(idx, off);
                if (ov > m || (ov == m && oi < idx)) { m = ov; idx = oi; }
            }
            float s = expf(v0 - m) + expf(v1 - m);
            #pragma unroll
            for (int off = 1; off < 32; off <<= 1) s += __shfl_xor(s, off);
            float ls = logf(s);
            float lr0 = fmaxf(v0 - m - ls, -18.4206807f);  // log(1e-8)
            float lr1 = fmaxf(v1 - m - ls, -18.4206807f);
            *(float2*)&log_resp[(size_t)row * KK + k0] = make_float2(lr0, lr1);
            if (tc == 0) {
                a_s[tr * 8 + i] = idx;
                atomicAdd(&lh[idx], 1);
            }
        }
    }
    __syncthreads();
    if (tid < KK) bhist[b * KK + tid] = lh[tid];   // [block][k], coalesced
    __threadfence();
    grid.sync();

    // ---------------- Phase B ----------------
    {
        int t = tid & 63, q = tid >> 6;
        int tot = 0, pre = 0;
        const int bb0 = q * 64;
        for (int bb = bb0; bb < bb0 + 64; ++bb) {
            int v = bhist[bb * KK + t];          // lanes t consecutive: coalesced
            tot += v;
            if (bb < b) pre += v;
        }
        ph_tot[q][t] = tot; ph_pre[q][t] = pre;
    }
    __syncthreads();
    if (tid < KK) {
        m_cnt[tid] = ph_tot[0][tid] + ph_tot[1][tid] + ph_tot[2][tid] + ph_tot[3][tid];
        m_pre[tid] = ph_pre[0][tid] + ph_pre[1][tid] + ph_pre[2][tid] + ph_pre[3][tid];
        lh[tid] = 0;                              // reuse as scatter cursor
    }
    __syncthreads();
    if (tid == 0) {
        int base = 0, ic = 0;
        m_item[0] = -1;
        for (int k = 0; k < KK; ++k) {
            m_base[k] = base; base += m_cnt[k];
            m_ist[k] = ic;
            int ns = (m_cnt[k] + SEG - 1) / SEG;
            if (b >= ic && b < ic + ns) { m_item[0] = k; m_item[1] = b - ic; }
            ic += ns;
            m_ien[k] = ic;
        }
    }
    __syncthreads();
    if (tid < 64) {                               // scatter own 64 rows
        int a = a_s[tid];
        int p = m_base[a] + m_pre[a] + atomicAdd(&lh[a], 1);
        sorted[p] = row0 + tid;                   // intra-cluster order: don't care
    }
    __threadfence();
    grid.sync();

    // ---------------- Phase C ----------------
    if (m_item[0] >= 0) {
        const int k = m_item[0], seg = m_item[1];
        const int gstart = m_base[k] + seg * SEG;
        const int len = min(SEG, m_cnt[k] - seg * SEG);

        if (tid < len) rows_s[tid] = sorted[gstart + tid];

        const int jrow = tid >> 5;
        const int dc   = (tid & 31) * 4;
        const int tr = tid >> 4, tc = tid & 15;

        float acc[8][8];
        #pragma unroll
        for (int i = 0; i < 8; ++i)
            #pragma unroll
            for (int l = 0; l < 8; ++l) acc[i][l] = 0.f;
        float cs0 = 0.f, cs1 = 0.f, cs2 = 0.f, cs3 = 0.f;

        __syncthreads();

        float4 cur = {0.f, 0.f, 0.f, 0.f};
        if (jrow < len)
            cur = *(const float4*)(x + (size_t)rows_s[jrow] * DD + dc);

        for (int it0 = 0; it0 < len; it0 += 8) {
            __syncthreads();
            *(float4*)&xr_s[jrow][dc] = cur;
            cs0 += cur.x; cs1 += cur.y; cs2 += cur.z; cs3 += cur.w;
            __syncthreads();

            float4 nxt = {0.f, 0.f, 0.f, 0.f};
            int mi = it0 + 8 + jrow;
            if (mi < len)
                nxt = *(const float4*)(x + (size_t)rows_s[mi] * DD + dc);

            #pragma unroll
            for (int j = 0; j < 8; ++j) {
                float4 a0 = *(const float4*)&xr_s[j][tr * 8];
                float4 a1 = *(const float4*)&xr_s[j][tr * 8 + 4];
                float4 b0 = *(const float4*)&xr_s[j][tc * 8];
                float4 b1 = *(const float4*)&xr_s[j][tc * 8 + 4];
                float av[8] = {a0.x, a0.y, a0.z, a0.w, a1.x, a1.y, a1.z, a1.w};
                float bv[8] = {b0.x, b0.y, b0.z, b0.w, b1.x, b1.y, b1.z, b1.w};
                #pragma unroll
                for (int i = 0; i < 8; ++i)
                    #pragma unroll
                    for (int l = 0; l < 8; ++l)
                        acc[i][l] = fmaf(av[i], bv[l], acc[i][l]);
            }
            cur = nxt;
        }

        float* pb = part + (size_t)b * (DD * DD);
        #pragma unroll
        for (int i = 0; i < 8; ++i) {
            #pragma unroll
            for (int l = 0; l < 8; l += 4)
                *(float4*)&pb[(tr * 8 + i) * DD + tc * 8 + l] = *(float4*)&acc[i][l];
        }

        __syncthreads();
        xr_s[jrow][dc + 0] = cs0; xr_s[jrow][dc + 1] = cs1;
        xr_s[jrow][dc + 2] = cs2; xr_s[jrow][dc + 3] = cs3;
        __syncthreads();
        if (tid < 32) {
            float4 t = {0.f, 0.f, 0.f, 0.f};
            #pragma unroll
            for (int j = 0; j < 8; ++j) {
                float4 v = *(const float4*)&xr_s[j][tid * 4];
                t.x += v.x; t.y += v.y; t.z += v.z; t.w += v.w;
            }
            atomicAdd(&emp[k * DD + tid * 4 + 0], t.x);
            atomicAdd(&emp[k * DD + tid * 4 + 1], t.y);
            atomicAdd(&emp[k * DD + tid * 4 + 2], t.z);
            atomicAdd(&emp[k * DD + tid * 4 + 3], t.w);
        }
    }
    __threadfence();
    grid.sync();

    // ---------------- Phase D ----------------
    {
        const int kD = b >> 2, p = b & 3;
        const int i0 = m_ist[kD], i1 = m_ien[kD];
        const int w = tid >> 6, lane = tid & 63;
        const float wgt = (float)m_cnt[kD];
        const float inv = 1.0f / (wgt + 1e-7f);

        if (tid < DD) {
            float e = emp[kD * DD + tid];
            emp_s[tid] = e;
            mu_s[tid] = e * inv;
        }

        float4 acc[16];
        #pragma unroll
        for (int c = 0; c < 16; ++c) acc[c] = make_float4(0.f, 0.f, 0.f, 0.f);

        for (int it = i0 + w; it < i1; it += 4) {
            const float* pb = part + (size_t)it * (DD * DD) + p * 4096;
            #pragma unroll
            for (int c = 0; c < 16; ++c) {
                float4 v = *(const float4*)&pb[c * 256 + lane * 4];
                acc[c].x += v.x; acc[c].y += v.y; acc[c].z += v.z; acc[c].w += v.w;
            }
        }
        #pragma unroll
        for (int c = 0; c < 16; ++c)
            *(float4*)&red[w][c * 256 + lane * 4] = acc[c];
        __syncthreads();

        float ds = 0.f, os = 0.f, mm = 0.f;
        #pragma unroll
        for (int jj = 0; jj < 16; ++jj) {
            int el = jj * 256 + tid;               // stride-1 across lanes
            float sx = red[0][el] + red[1][el] + red[2][el] + red[3][el];
            int gel = p * 4096 + el;
            int d = gel >> 7, e = gel & 127;
            float ctv = sx - mu_s[d] * emp_s[e] - emp_s[d] * mu_s[e]
                      + wgt * mu_s[d] * mu_s[e];
            float v = ctv * inv;
            if (d == e) { float t2 = v - 1.f; ds += t2 * t2; }
            else        { os += v * v; }
        }
        if (p == 0 && tid < DD) {
            float t2 = mu_s[tid] - centers[kD * DD + tid];
            mm = t2 * t2;
        }

        #pragma unroll
        for (int off = 32; off > 0; off >>= 1) {
            ds += __shfl_down(ds, off);
            os += __shfl_down(os, off);
            mm += __shfl_down(mm, off);
        }
        if (lane == 0) { rds[w] = ds; ros[w] = os; rmm[w] = mm; }
        __syncthreads();
        if (tid == 0) {
            float DS = rds[0] + rds[1] + rds[2] + rds[3];
            float OS = ros[0] + ros[1] + ros[2] + ros[3];
            float MM = rmm[0] + rmm[1] + rmm[2] + rmm[3];
            const float bd = (float)BB * (float)DD;
            atomicAdd(&outscalars[0], wgt * MM / bd);
            atomicAdd(&outscalars[1], wgt * DS / bd + wgt * OS / (bd * (float)(DD - 1)));
        }
    }
}

// ---------------------------------------------------------------------------
extern "C" void kernel_launch(void* const* d_in, const int* in_sizes, int n_in,
                              void* d_out, int out_size, void* d_ws, size_t ws_size,
                              hipStream_t stream) {
    const float* x = (const float*)d_in[0];
    const float* centers = (const float*)d_in[1];
    float* out = (float*)d_out;
    float* outscalars = out + (size_t)BB * KK;

    char* ws = (char*)d_ws;
    size_t off = 0;
    float* part   = (float*)(ws + off); off += (size_t)NBLK * DD * DD * 4;  // 16 MB
    float* emp    = (float*)(ws + off); off += KK * DD * 4;                 // 32 KB
    int*   sorted = (int*)  (ws + off); off += BB * 4;                      // 64 KB
    int*   bhist  = (int*)  (ws + off); off += NBLK * KK * 4;               // 64 KB

    void* args[] = {
        (void*)&x, (void*)&centers, (void*)&out, (void*)&outscalars,
        (void*)&sorted, (void*)&bhist, (void*)&part, (void*)&emp
    };
    hipLaunchCooperativeKernel((const void*)k_fused, dim3(NBLK), dim3(256),
                               args, 0, stream);
}

// Round 8
// 140.723 us; speedup vs baseline: 2.0610x; 2.0610x over previous
//
#include <hip/hip_runtime.h>

#define BB 16384
#define KK 64
#define DD 128
#define SEG 128          // rows per covariance work-item
#define MAXITEMS 256     // sum_k ceil(cnt_k/SEG) <= 128 + 63 = 191
#define RSLAB 2048       // elements per reduce slab (8 slabs of 128x128)

// ---------------------------------------------------------------------------
// K1: tiled GEMM. Block = 64 rows x 64 clusters, K=128.
// dist = |x|^2 - 2 x.c + |c|^2 ; |x|^2 cancels in softmax AND argmin.
// Emits per-block cluster histogram bhist[b][k] for the parallel scatter.
// Also zeroes outscalars + emp[] (consumed >=2 dispatches later).
// ---------------------------------------------------------------------------
__global__ __launch_bounds__(256) void k_rows(
    const float* __restrict__ x, const float* __restrict__ centers,
    float* __restrict__ log_resp, int* __restrict__ assign,
    int* __restrict__ bhist, float* __restrict__ outscalars,
    float* __restrict__ emp)
{
    __shared__ float xs[64][132];    // X tile, +4 pad
    __shared__ float ct[DD][66];     // centers transposed [d][k]
    __shared__ float cn2[KK];
    __shared__ int   lh[KK];

    const int tid = threadIdx.x;
    const int row0 = blockIdx.x * 64;

    if (blockIdx.x == 0 && tid < 2) outscalars[tid] = 0.f;
    if (tid < 32) emp[blockIdx.x * 32 + tid] = 0.f;   // 256*32 = 8192
    if (tid < KK) lh[tid] = 0;

    for (int g = tid; g < 64 * 32; g += 256) {
        int r = g >> 5, c4 = g & 31;
        float4 v = ((const float4*)(x + (size_t)(row0 + r) * DD))[c4];
        *(float4*)&xs[r][c4 * 4] = v;
    }
    for (int g = tid; g < KK * 32; g += 256) {
        int k = g >> 5, c4 = g & 31;
        float4 v = ((const float4*)(centers + (size_t)k * DD))[c4];
        ct[c4 * 4 + 0][k] = v.x;
        ct[c4 * 4 + 1][k] = v.y;
        ct[c4 * 4 + 2][k] = v.z;
        ct[c4 * 4 + 3][k] = v.w;
    }
    __syncthreads();
    if (tid < KK) {
        float s = 0.f;
        for (int d = 0; d < DD; ++d) { float c = ct[d][tid]; s = fmaf(c, c, s); }
        cn2[tid] = s;
    }
    __syncthreads();

    const int tr = tid >> 5;
    const int tc = tid & 31;
    const int k0 = tc * 2, k1 = k0 + 1;

    float acc0[8], acc1[8];
    #pragma unroll
    for (int i = 0; i < 8; ++i) { acc0[i] = 0.f; acc1[i] = 0.f; }

    for (int d = 0; d < DD; d += 4) {
        float2 b0 = *(const float2*)&ct[d + 0][k0];
        float2 b1 = *(const float2*)&ct[d + 1][k0];
        float2 b2 = *(const float2*)&ct[d + 2][k0];
        float2 b3 = *(const float2*)&ct[d + 3][k0];
        #pragma unroll
        for (int i = 0; i < 8; ++i) {
            float4 a = *(const float4*)&xs[tr * 8 + i][d];
            acc0[i] = fmaf(a.x, b0.x, acc0[i]);
            acc1[i] = fmaf(a.x, b0.y, acc1[i]);
            acc0[i] = fmaf(a.y, b1.x, acc0[i]);
            acc1[i] = fmaf(a.y, b1.y, acc1[i]);
            acc0[i] = fmaf(a.z, b2.x, acc0[i]);
            acc1[i] = fmaf(a.z, b2.y, acc1[i]);
            acc0[i] = fmaf(a.w, b3.x, acc0[i]);
            acc1[i] = fmaf(a.w, b3.y, acc1[i]);
        }
    }

    const float cn0 = 0.5f * cn2[k0], cn1 = 0.5f * cn2[k1];
    #pragma unroll
    for (int i = 0; i < 8; ++i) {
        int row = row0 + tr * 8 + i;
        float v0 = acc0[i] - cn0;
        float v1 = acc1[i] - cn1;
        float m; int idx;
        if (v1 > v0) { m = v1; idx = k1; } else { m = v0; idx = k0; }
        #pragma unroll
        for (int off = 1; off < 32; off <<= 1) {
            float ov = __shfl_xor(m, off);
            int   oi = __shfl_xor(idx, off);
            if (ov > m || (ov == m && oi < idx)) { m = ov; idx = oi; }
        }
        float s = expf(v0 - m) + expf(v1 - m);
        #pragma unroll
        for (int off = 1; off < 32; off <<= 1) s += __shfl_xor(s, off);
        float ls = logf(s);
        float lr0 = fmaxf(v0 - m - ls, -18.4206807f);  // log(1e-8)
        float lr1 = fmaxf(v1 - m - ls, -18.4206807f);
        *(float2*)&log_resp[(size_t)row * KK + k0] = make_float2(lr0, lr1);
        if (tc == 0) {
            assign[row] = idx;
            atomicAdd(&lh[idx], 1);
        }
    }
    __syncthreads();
    if (tid < KK) bhist[blockIdx.x * KK + tid] = lh[tid];   // coalesced 256B
}

// ---------------------------------------------------------------------------
// K2 (256 blocks): parallel counting-sort scatter. Every block redundantly
// computes per-cluster totals + its own exclusive prefix from bhist
// (coalesced, split over 4 waves), then scatters its 64 rows. Block 0 also
// emits items / ist / ien / itemcnt / cw. (R6's single-block k_sort was the
// largest non-fill kernel; this spreads it across 256 CUs.)
// ---------------------------------------------------------------------------
__global__ __launch_bounds__(256) void k_scat(
    const int* __restrict__ assign, const int* __restrict__ bhist,
    int* __restrict__ sorted, float* __restrict__ cw,
    int4* __restrict__ items, int* __restrict__ item_count,
    int* __restrict__ ist, int* __restrict__ ien)
{
    __shared__ int ph_tot[4][KK], ph_pre[4][KK];
    __shared__ int cnt_s[KK], pre_s[KK], base_s[KK], cur_s[KK];

    const int tid = threadIdx.x;
    const int b = blockIdx.x;
    const int t = tid & 63, q = tid >> 6;

    int tot = 0, pre = 0;
    const int bb0 = q * 64;
    for (int bb = bb0; bb < bb0 + 64; ++bb) {
        int v = bhist[bb * KK + t];          // lanes consecutive: coalesced
        tot += v;
        if (bb < b) pre += v;
    }
    ph_tot[q][t] = tot; ph_pre[q][t] = pre;
    __syncthreads();

    if (tid < KK) {
        cnt_s[tid] = ph_tot[0][tid] + ph_tot[1][tid] + ph_tot[2][tid] + ph_tot[3][tid];
        pre_s[tid] = ph_pre[0][tid] + ph_pre[1][tid] + ph_pre[2][tid] + ph_pre[3][tid];
        cur_s[tid] = 0;
    }
    __syncthreads();
    if (tid == 0) {
        int base = 0;
        for (int k = 0; k < KK; ++k) { base_s[k] = base; base += cnt_s[k]; }
    }
    __syncthreads();

    if (tid < 64) {
        int r = b * 64 + tid;
        int a = assign[r];
        int p = base_s[a] + pre_s[a] + atomicAdd(&cur_s[a], 1);
        sorted[p] = r;                       // intra-cluster order: don't care
    }

    if (b == 0) {
        if (tid < KK) cw[tid] = (float)cnt_s[tid];
        if (tid == 0) {
            int ic = 0;
            for (int k = 0; k < KK; ++k) {
                ist[k] = ic;
                int c = cnt_s[k];
                for (int s = 0; s < c; s += SEG) {
                    int4 it; it.x = k; it.y = base_s[k] + s;
                    it.z = min(SEG, c - s); it.w = 0;
                    items[ic++] = it;
                }
                ien[k] = ic;
            }
            *item_count = ic;
        }
    }
}

// ---------------------------------------------------------------------------
// K3: one block per item (<=128 rows), FULL 128x128 partial via 8x8 thread
// tiles. Register prefetch hides the scattered global x latency behind
// compute. Column sums atomically into emp[] (zeroed by k_rows).
// ---------------------------------------------------------------------------
__global__ __launch_bounds__(256) void k_seg(
    const float* __restrict__ x, const int* __restrict__ sorted,
    const int4* __restrict__ items, const int* __restrict__ item_count,
    float* __restrict__ part, float* __restrict__ emp)
{
    if ((int)blockIdx.x >= *item_count) return;
    int4 it = items[blockIdx.x];
    const int k = it.x, gstart = it.y, len = it.z;

    __shared__ int rows_s[SEG];
    __shared__ float xr_s[8][DD];

    const int tid = threadIdx.x;
    if (tid < len) rows_s[tid] = sorted[gstart + tid];

    const int jrow = tid >> 5;            // 0..7: staged row this thread loads
    const int dc   = (tid & 31) * 4;      // float4 column offset
    const int tr = tid >> 4, tc = tid & 15;

    float acc[8][8];
    #pragma unroll
    for (int i = 0; i < 8; ++i)
        #pragma unroll
        for (int l = 0; l < 8; ++l) acc[i][l] = 0.f;
    float cs0 = 0.f, cs1 = 0.f, cs2 = 0.f, cs3 = 0.f;

    __syncthreads();   // rows_s ready

    float4 cur = {0.f, 0.f, 0.f, 0.f};
    if (jrow < len)
        cur = *(const float4*)(x + (size_t)rows_s[jrow] * DD + dc);

    for (int it0 = 0; it0 < len; it0 += 8) {
        __syncthreads();   // WAR on xr_s
        *(float4*)&xr_s[jrow][dc] = cur;
        cs0 += cur.x; cs1 += cur.y; cs2 += cur.z; cs3 += cur.w;
        __syncthreads();   // RAW

        float4 nxt = {0.f, 0.f, 0.f, 0.f};
        int mi = it0 + 8 + jrow;
        if (mi < len)
            nxt = *(const float4*)(x + (size_t)rows_s[mi] * DD + dc);

        #pragma unroll
        for (int j = 0; j < 8; ++j) {
            float4 a0 = *(const float4*)&xr_s[j][tr * 8];
            float4 a1 = *(const float4*)&xr_s[j][tr * 8 + 4];
            float4 b0 = *(const float4*)&xr_s[j][tc * 8];
            float4 b1 = *(const float4*)&xr_s[j][tc * 8 + 4];
            float av[8] = {a0.x, a0.y, a0.z, a0.w, a1.x, a1.y, a1.z, a1.w};
            float bv[8] = {b0.x, b0.y, b0.z, b0.w, b1.x, b1.y, b1.z, b1.w};
            #pragma unroll
            for (int i = 0; i < 8; ++i)
                #pragma unroll
                for (int l = 0; l < 8; ++l)
                    acc[i][l] = fmaf(av[i], bv[l], acc[i][l]);
        }
        cur = nxt;
    }

    float* pb = part + (size_t)blockIdx.x * (DD * DD);
    #pragma unroll
    for (int i = 0; i < 8; ++i) {
        #pragma unroll
        for (int l = 0; l < 8; l += 4)
            *(float4*)&pb[(tr * 8 + i) * DD + tc * 8 + l] = *(float4*)&acc[i][l];
    }

    __syncthreads();
    xr_s[jrow][dc + 0] = cs0; xr_s[jrow][dc + 1] = cs1;
    xr_s[jrow][dc + 2] = cs2; xr_s[jrow][dc + 3] = cs3;
    __syncthreads();
    if (tid < 32) {
        float4 t = {0.f, 0.f, 0.f, 0.f};
        #pragma unroll
        for (int j = 0; j < 8; ++j) {
            float4 v = *(const float4*)&xr_s[j][tid * 4];
            t.x += v.x; t.y += v.y; t.z += v.z; t.w += v.w;
        }
        atomicAdd(&emp[k * DD + tid * 4 + 0], t.x);
        atomicAdd(&emp[k * DD + tid * 4 + 1], t.y);
        atomicAdd(&emp[k * DD + tid * 4 + 2], t.z);
        atomicAdd(&emp[k * DD + tid * 4 + 3], t.w);
    }
}

// ---------------------------------------------------------------------------
// K4: grid = KK x 8 slabs (2048 elems). Items split across the 4 waves;
// within an item the wave streams the slab as contiguous coalesced float4
// transactions with 8 independent acc chains. Cross-wave combine in LDS,
// then centered covariance + scalar accumulate. (R5's item-major strided
// gather was 58us @ 98GB/s; this streaming layout measured fine in R6.)
// ---------------------------------------------------------------------------
__global__ __launch_bounds__(256) void k_redfinal(
    const float* __restrict__ part, const float* __restrict__ emp,
    const float* __restrict__ cw, const float* __restrict__ centers,
    const int* __restrict__ ist, const int* __restrict__ ien,
    float* __restrict__ outscalars)
{
    const int k = blockIdx.x >> 3;
    const int p = blockIdx.x & 7;
    const int i0 = ist[k], i1 = ien[k];
    const int tid = threadIdx.x;
    const int w = tid >> 6, lane = tid & 63;
    const float wgt = cw[k];
    const float inv = 1.0f / (wgt + 1e-7f);

    __shared__ float mu_s[DD], emp_s[DD];
    __shared__ float red[4][RSLAB];      // 32 KB

    if (tid < DD) {
        float e = emp[k * DD + tid];
        emp_s[tid] = e;
        mu_s[tid] = e * inv;
    }

    float4 acc[8];
    #pragma unroll
    for (int c = 0; c < 8; ++c) acc[c] = make_float4(0.f, 0.f, 0.f, 0.f);

    const int base = p * RSLAB;
    for (int it = i0 + w; it < i1; it += 4) {
        const float* pb = part + (size_t)it * (DD * DD) + base;
        #pragma unroll
        for (int c = 0; c < 8; ++c) {
            float4 v = *(const float4*)&pb[c * 256 + lane * 4];
            acc[c].x += v.x; acc[c].y += v.y; acc[c].z += v.z; acc[c].w += v.w;
        }
    }
    #pragma unroll
    for (int c = 0; c < 8; ++c)
        *(float4*)&red[w][c * 256 + lane * 4] = acc[c];
    __syncthreads();

    float ds = 0.f, os = 0.f, mm = 0.f;
    #pragma unroll
    for (int jj = 0; jj < 8; ++jj) {
        int el = jj * 256 + tid;               // stride-1 across lanes
        float sx = red[0][el] + red[1][el] + red[2][el] + red[3][el];
        int gel = base + el;
        int d = gel >> 7, e = gel & 127;
        float ctv = sx - mu_s[d] * emp_s[e] - emp_s[d] * mu_s[e]
                  + wgt * mu_s[d] * mu_s[e];
        float v = ctv * inv;
        if (d == e) { float t = v - 1.f; ds += t * t; }
        else        { os += v * v; }
    }
    if (p == 0 && tid < DD) {
        float t = mu_s[tid] - centers[k * DD + tid];
        mm = t * t;
    }

    #pragma unroll
    for (int off = 32; off > 0; off >>= 1) {
        ds += __shfl_down(ds, off);
        os += __shfl_down(os, off);
        mm += __shfl_down(mm, off);
    }
    __shared__ float rds[4], ros[4], rmm[4];
    if (lane == 0) { rds[w] = ds; ros[w] = os; rmm[w] = mm; }
    __syncthreads();
    if (tid == 0) {
        float DS = rds[0] + rds[1] + rds[2] + rds[3];
        float OS = ros[0] + ros[1] + ros[2] + ros[3];
        float MM = rmm[0] + rmm[1] + rmm[2] + rmm[3];
        const float bd = (float)BB * (float)DD;
        atomicAdd(&outscalars[0], wgt * MM / bd);
        atomicAdd(&outscalars[1], wgt * DS / bd + wgt * OS / (bd * (float)(DD - 1)));
    }
}

// ---------------------------------------------------------------------------
extern "C" void kernel_launch(void* const* d_in, const int* in_sizes, int n_in,
                              void* d_out, int out_size, void* d_ws, size_t ws_size,
                              hipStream_t stream) {
    const float* x = (const float*)d_in[0];
    const float* centers = (const float*)d_in[1];
    float* out = (float*)d_out;
    float* outscalars = out + (size_t)BB * KK;

    char* ws = (char*)d_ws;
    size_t off = 0;
    float* part    = (float*)(ws + off); off += (size_t)MAXITEMS * DD * DD * 4; // 16 MB
    float* emp     = (float*)(ws + off); off += KK * DD * 4;                    // 32 KB
    int*   sorted  = (int*)  (ws + off); off += BB * 4;                         // 64 KB
    int*   assign  = (int*)  (ws + off); off += BB * 4;                         // 64 KB
    int*   bhist   = (int*)  (ws + off); off += 256 * KK * 4;                   // 64 KB
    int4*  items   = (int4*) (ws + off); off += MAXITEMS * 16;
    float* cw      = (float*)(ws + off); off += 256;
    int*   itemcnt = (int*)  (ws + off); off += 256;
    int*   ist     = (int*)  (ws + off); off += 256;
    int*   ien     = (int*)  (ws + off); off += 256;

    k_rows    <<<256, 256, 0, stream>>>(x, centers, out, assign, bhist,
                                        outscalars, emp);
    k_scat    <<<256, 256, 0, stream>>>(assign, bhist, sorted, cw, items,
                                        itemcnt, ist, ien);
    k_seg     <<<MAXITEMS, 256, 0, stream>>>(x, sorted, items, itemcnt, part, emp);
    k_redfinal<<<KK * 8, 256, 0, stream>>>(part, emp, cw, centers, ist, ien,
                                           outscalars);
}

// Round 9
// 128.339 us; speedup vs baseline: 2.2598x; 1.0965x over previous
//
#include <hip/hip_runtime.h>

#define BB 16384
#define KK 64
#define DD 128
#define SEG 128          // rows per covariance work-item
#define MAXITEMS 256     // sum_k ceil(cnt_k/SEG) <= 128 + 63 = 191
#define RSLAB 2048       // elements per reduce slab (8 slabs of 128x128)

typedef __attribute__((ext_vector_type(8))) short bf16x8;
typedef __attribute__((ext_vector_type(4))) float f32x4;

__device__ __forceinline__ unsigned int packbf2(float a, float b) {
    unsigned ua = __float_as_uint(a);
    unsigned ub = __float_as_uint(b);
    ua = (ua + 0x7FFFu + ((ua >> 16) & 1u)) >> 16;   // RNE f32->bf16
    ub = (ub + 0x7FFFu + ((ub >> 16) & 1u)) >> 16;
    return ua | (ub << 16);
}

// ---------------------------------------------------------------------------
// K1: tiled GEMM. Block = 64 rows x 64 clusters, K=128.
// dist = |x|^2 - 2 x.c + |c|^2 ; |x|^2 cancels in softmax AND argmin.
// Emits per-block cluster histogram bhist[b][k] for the parallel scatter.
// Also zeroes outscalars + emp[] (consumed >=2 dispatches later).
// ---------------------------------------------------------------------------
__global__ __launch_bounds__(256) void k_rows(
    const float* __restrict__ x, const float* __restrict__ centers,
    float* __restrict__ log_resp, int* __restrict__ assign,
    int* __restrict__ bhist, float* __restrict__ outscalars,
    float* __restrict__ emp)
{
    __shared__ float xs[64][132];    // X tile, +4 pad
    __shared__ float ct[DD][66];     // centers transposed [d][k]
    __shared__ float cn2[KK];
    __shared__ int   lh[KK];

    const int tid = threadIdx.x;
    const int row0 = blockIdx.x * 64;

    if (blockIdx.x == 0 && tid < 2) outscalars[tid] = 0.f;
    if (tid < 32) emp[blockIdx.x * 32 + tid] = 0.f;   // 256*32 = 8192
    if (tid < KK) lh[tid] = 0;

    for (int g = tid; g < 64 * 32; g += 256) {
        int r = g >> 5, c4 = g & 31;
        float4 v = ((const float4*)(x + (size_t)(row0 + r) * DD))[c4];
        *(float4*)&xs[r][c4 * 4] = v;
    }
    for (int g = tid; g < KK * 32; g += 256) {
        int k = g >> 5, c4 = g & 31;
        float4 v = ((const float4*)(centers + (size_t)k * DD))[c4];
        ct[c4 * 4 + 0][k] = v.x;
        ct[c4 * 4 + 1][k] = v.y;
        ct[c4 * 4 + 2][k] = v.z;
        ct[c4 * 4 + 3][k] = v.w;
    }
    __syncthreads();
    if (tid < KK) {
        float s = 0.f;
        for (int d = 0; d < DD; ++d) { float c = ct[d][tid]; s = fmaf(c, c, s); }
        cn2[tid] = s;
    }
    __syncthreads();

    const int tr = tid >> 5;
    const int tc = tid & 31;
    const int k0 = tc * 2, k1 = k0 + 1;

    float acc0[8], acc1[8];
    #pragma unroll
    for (int i = 0; i < 8; ++i) { acc0[i] = 0.f; acc1[i] = 0.f; }

    for (int d = 0; d < DD; d += 4) {
        float2 b0 = *(const float2*)&ct[d + 0][k0];
        float2 b1 = *(const float2*)&ct[d + 1][k0];
        float2 b2 = *(const float2*)&ct[d + 2][k0];
        float2 b3 = *(const float2*)&ct[d + 3][k0];
        #pragma unroll
        for (int i = 0; i < 8; ++i) {
            float4 a = *(const float4*)&xs[tr * 8 + i][d];
            acc0[i] = fmaf(a.x, b0.x, acc0[i]);
            acc1[i] = fmaf(a.x, b0.y, acc1[i]);
            acc0[i] = fmaf(a.y, b1.x, acc0[i]);
            acc1[i] = fmaf(a.y, b1.y, acc1[i]);
            acc0[i] = fmaf(a.z, b2.x, acc0[i]);
            acc1[i] = fmaf(a.z, b2.y, acc1[i]);
            acc0[i] = fmaf(a.w, b3.x, acc0[i]);
            acc1[i] = fmaf(a.w, b3.y, acc1[i]);
        }
    }

    const float cn0 = 0.5f * cn2[k0], cn1 = 0.5f * cn2[k1];
    #pragma unroll
    for (int i = 0; i < 8; ++i) {
        int row = row0 + tr * 8 + i;
        float v0 = acc0[i] - cn0;
        float v1 = acc1[i] - cn1;
        float m; int idx;
        if (v1 > v0) { m = v1; idx = k1; } else { m = v0; idx = k0; }
        #pragma unroll
        for (int off = 1; off < 32; off <<= 1) {
            float ov = __shfl_xor(m, off);
            int   oi = __shfl_xor(idx, off);
            if (ov > m || (ov == m && oi < idx)) { m = ov; idx = oi; }
        }
        float s = expf(v0 - m) + expf(v1 - m);
        #pragma unroll
        for (int off = 1; off < 32; off <<= 1) s += __shfl_xor(s, off);
        float ls = logf(s);
        float lr0 = fmaxf(v0 - m - ls, -18.4206807f);  // log(1e-8)
        float lr1 = fmaxf(v1 - m - ls, -18.4206807f);
        *(float2*)&log_resp[(size_t)row * KK + k0] = make_float2(lr0, lr1);
        if (tc == 0) {
            assign[row] = idx;
            atomicAdd(&lh[idx], 1);
        }
    }
    __syncthreads();
    if (tid < KK) bhist[blockIdx.x * KK + tid] = lh[tid];   // coalesced 256B
}

// ---------------------------------------------------------------------------
// K2 (256 blocks): parallel counting-sort scatter (see R8 notes).
// ---------------------------------------------------------------------------
__global__ __launch_bounds__(256) void k_scat(
    const int* __restrict__ assign, const int* __restrict__ bhist,
    int* __restrict__ sorted, float* __restrict__ cw,
    int4* __restrict__ items, int* __restrict__ item_count,
    int* __restrict__ ist, int* __restrict__ ien)
{
    __shared__ int ph_tot[4][KK], ph_pre[4][KK];
    __shared__ int cnt_s[KK], pre_s[KK], base_s[KK], cur_s[KK];

    const int tid = threadIdx.x;
    const int b = blockIdx.x;
    const int t = tid & 63, q = tid >> 6;

    int tot = 0, pre = 0;
    const int bb0 = q * 64;
    for (int bb = bb0; bb < bb0 + 64; ++bb) {
        int v = bhist[bb * KK + t];          // lanes consecutive: coalesced
        tot += v;
        if (bb < b) pre += v;
    }
    ph_tot[q][t] = tot; ph_pre[q][t] = pre;
    __syncthreads();

    if (tid < KK) {
        cnt_s[tid] = ph_tot[0][tid] + ph_tot[1][tid] + ph_tot[2][tid] + ph_tot[3][tid];
        pre_s[tid] = ph_pre[0][tid] + ph_pre[1][tid] + ph_pre[2][tid] + ph_pre[3][tid];
        cur_s[tid] = 0;
    }
    __syncthreads();
    if (tid == 0) {
        int base = 0;
        for (int k = 0; k < KK; ++k) { base_s[k] = base; base += cnt_s[k]; }
    }
    __syncthreads();

    if (tid < 64) {
        int r = b * 64 + tid;
        int a = assign[r];
        int p = base_s[a] + pre_s[a] + atomicAdd(&cur_s[a], 1);
        sorted[p] = r;                       // intra-cluster order: don't care
    }

    if (b == 0) {
        if (tid < KK) cw[tid] = (float)cnt_s[tid];
        if (tid == 0) {
            int ic = 0;
            for (int k = 0; k < KK; ++k) {
                ist[k] = ic;
                int c = cnt_s[k];
                for (int s = 0; s < c; s += SEG) {
                    int4 it; it.x = k; it.y = base_s[k] + s;
                    it.z = min(SEG, c - s); it.w = 0;
                    items[ic++] = it;
                }
                ien[k] = ic;
            }
            *item_count = ic;
        }
    }
}

// ---------------------------------------------------------------------------
// K3 (MFMA): one block per item (<=128 rows). Stage rows as transposed bf16
// tile XT[dim][row-pair u32] (PAD=68 u32: 16B-aligned rows, conflict-free
// writes). Sxx = X^T X via mfma_f32_16x16x32_bf16: both A and B fragments are
// the SAME contiguous b128 read pattern (A[m=lane&15][k=q*8+j], B mirrored) —
// a transpose mix-up is benign since Sxx is symmetric. Column sums in f32
// from the identical bf16 data -> emp atomics. Replaces ~524K VALU FMAs
// per block (LDS-pipe bound, 4-way conflicted) with 256 MFMAs.
// ---------------------------------------------------------------------------
__global__ __launch_bounds__(256) void k_seg(
    const float* __restrict__ x, const int* __restrict__ sorted,
    const int4* __restrict__ items, const int* __restrict__ item_count,
    float* __restrict__ part, float* __restrict__ emp)
{
    if ((int)blockIdx.x >= *item_count) return;
    int4 it = items[blockIdx.x];
    const int k = it.x, gstart = it.y, len = it.z;

    __shared__ int rows_s[SEG];
    __shared__ unsigned int XT[DD][68];   // XT[d][j] = bf16 pair rows (2j, 2j+1)

    const int tid = threadIdx.x;
    const int w = tid >> 6, lane = tid & 63;

    if (tid < len) rows_s[tid] = sorted[gstart + tid];
    __syncthreads();

    // stage: wave w owns dims [w*32, w*32+32); lane owns row pair (2L, 2L+1)
    {
        const int r0 = 2 * lane, r1 = 2 * lane + 1;
        const int d0 = w * 32;
        const float* p0 = x + (size_t)rows_s[r0 < len ? r0 : 0] * DD + d0;
        const float* p1 = x + (size_t)rows_s[r1 < len ? r1 : 0] * DD + d0;
        #pragma unroll
        for (int i = 0; i < 8; ++i) {
            float4 a = make_float4(0.f, 0.f, 0.f, 0.f);
            float4 b = make_float4(0.f, 0.f, 0.f, 0.f);
            if (r0 < len) a = *(const float4*)(p0 + 4 * i);
            if (r1 < len) b = *(const float4*)(p1 + 4 * i);
            XT[d0 + 4 * i + 0][lane] = packbf2(a.x, b.x);
            XT[d0 + 4 * i + 1][lane] = packbf2(a.y, b.y);
            XT[d0 + 4 * i + 2][lane] = packbf2(a.z, b.z);
            XT[d0 + 4 * i + 3][lane] = packbf2(a.w, b.w);
        }
    }
    __syncthreads();

    // column sums (f32, from the same bf16 data): thread d < 128
    if (tid < DD) {
        float s = 0.f;
        #pragma unroll
        for (int j4 = 0; j4 < 16; ++j4) {
            uint4 v = *(const uint4*)&XT[tid][j4 * 4];
            s += __uint_as_float(v.x << 16) + __uint_as_float(v.x & 0xFFFF0000u);
            s += __uint_as_float(v.y << 16) + __uint_as_float(v.y & 0xFFFF0000u);
            s += __uint_as_float(v.z << 16) + __uint_as_float(v.z & 0xFFFF0000u);
            s += __uint_as_float(v.w << 16) + __uint_as_float(v.w & 0xFFFF0000u);
        }
        atomicAdd(&emp[k * DD + tid], s);
    }

    // MFMA: wave w owns m-tiles {2w, 2w+1} x n-tiles 0..7
    const int c4 = lane & 15, q = lane >> 4;
    f32x4 acc[2][8];
    #pragma unroll
    for (int h = 0; h < 2; ++h)
        #pragma unroll
        for (int nt = 0; nt < 8; ++nt)
            acc[h][nt] = (f32x4){0.f, 0.f, 0.f, 0.f};

    #pragma unroll
    for (int c = 0; c < 4; ++c) {          // K chunks of 32 rows
        const int ku = c * 16 + q * 4;     // u32 index: k0 = c*32 + q*8
        bf16x8 a0 = *(const bf16x8*)&XT[(2 * w + 0) * 16 + c4][ku];
        bf16x8 a1 = *(const bf16x8*)&XT[(2 * w + 1) * 16 + c4][ku];
        #pragma unroll
        for (int nt = 0; nt < 8; ++nt) {
            bf16x8 b = *(const bf16x8*)&XT[nt * 16 + c4][ku];
            acc[0][nt] = __builtin_amdgcn_mfma_f32_16x16x32_bf16(a0, b, acc[0][nt], 0, 0, 0);
            acc[1][nt] = __builtin_amdgcn_mfma_f32_16x16x32_bf16(a1, b, acc[1][nt], 0, 0, 0);
        }
    }

    // C/D layout: col = lane&15, row = quad*4 + reg  [m89/m91 verified]
    float* pb = part + (size_t)blockIdx.x * (DD * DD);
    #pragma unroll
    for (int h = 0; h < 2; ++h) {
        const int m0 = (2 * w + h) * 16 + q * 4;
        #pragma unroll
        for (int nt = 0; nt < 8; ++nt) {
            const int n = nt * 16 + c4;
            pb[(m0 + 0) * DD + n] = acc[h][nt].x;
            pb[(m0 + 1) * DD + n] = acc[h][nt].y;
            pb[(m0 + 2) * DD + n] = acc[h][nt].z;
            pb[(m0 + 3) * DD + n] = acc[h][nt].w;
        }
    }
}

// ---------------------------------------------------------------------------
// K4: grid = KK x 8 slabs (2048 elems). Streaming coalesced reduce of item
// partials (R6-verified layout), centered covariance, scalar accumulate.
// ---------------------------------------------------------------------------
__global__ __launch_bounds__(256) void k_redfinal(
    const float* __restrict__ part, const float* __restrict__ emp,
    const float* __restrict__ cw, const float* __restrict__ centers,
    const int* __restrict__ ist, const int* __restrict__ ien,
    float* __restrict__ outscalars)
{
    const int k = blockIdx.x >> 3;
    const int p = blockIdx.x & 7;
    const int i0 = ist[k], i1 = ien[k];
    const int tid = threadIdx.x;
    const int w = tid >> 6, lane = tid & 63;
    const float wgt = cw[k];
    const float inv = 1.0f / (wgt + 1e-7f);

    __shared__ float mu_s[DD], emp_s[DD];
    __shared__ float red[4][RSLAB];      // 32 KB

    if (tid < DD) {
        float e = emp[k * DD + tid];
        emp_s[tid] = e;
        mu_s[tid] = e * inv;
    }

    float4 acc[8];
    #pragma unroll
    for (int c = 0; c < 8; ++c) acc[c] = make_float4(0.f, 0.f, 0.f, 0.f);

    const int base = p * RSLAB;
    for (int it = i0 + w; it < i1; it += 4) {
        const float* pb = part + (size_t)it * (DD * DD) + base;
        #pragma unroll
        for (int c = 0; c < 8; ++c) {
            float4 v = *(const float4*)&pb[c * 256 + lane * 4];
            acc[c].x += v.x; acc[c].y += v.y; acc[c].z += v.z; acc[c].w += v.w;
        }
    }
    #pragma unroll
    for (int c = 0; c < 8; ++c)
        *(float4*)&red[w][c * 256 + lane * 4] = acc[c];
    __syncthreads();

    float ds = 0.f, os = 0.f, mm = 0.f;
    #pragma unroll
    for (int jj = 0; jj < 8; ++jj) {
        int el = jj * 256 + tid;               // stride-1 across lanes
        float sx = red[0][el] + red[1][el] + red[2][el] + red[3][el];
        int gel = base + el;
        int d = gel >> 7, e = gel & 127;
        float ctv = sx - mu_s[d] * emp_s[e] - emp_s[d] * mu_s[e]
                  + wgt * mu_s[d] * mu_s[e];
        float v = ctv * inv;
        if (d == e) { float t = v - 1.f; ds += t * t; }
        else        { os += v * v; }
    }
    if (p == 0 && tid < DD) {
        float t = mu_s[tid] - centers[k * DD + tid];
        mm = t * t;
    }

    #pragma unroll
    for (int off = 32; off > 0; off >>= 1) {
        ds += __shfl_down(ds, off);
        os += __shfl_down(os, off);
        mm += __shfl_down(mm, off);
    }
    __shared__ float rds[4], ros[4], rmm[4];
    if (lane == 0) { rds[w] = ds; ros[w] = os; rmm[w] = mm; }
    __syncthreads();
    if (tid == 0) {
        float DS = rds[0] + rds[1] + rds[2] + rds[3];
        float OS = ros[0] + ros[1] + ros[2] + ros[3];
        float MM = rmm[0] + rmm[1] + rmm[2] + rmm[3];
        const float bd = (float)BB * (float)DD;
        atomicAdd(&outscalars[0], wgt * MM / bd);
        atomicAdd(&outscalars[1], wgt * DS / bd + wgt * OS / (bd * (float)(DD - 1)));
    }
}

// ---------------------------------------------------------------------------
extern "C" void kernel_launch(void* const* d_in, const int* in_sizes, int n_in,
                              void* d_out, int out_size, void* d_ws, size_t ws_size,
                              hipStream_t stream) {
    const float* x = (const float*)d_in[0];
    const float* centers = (const float*)d_in[1];
    float* out = (float*)d_out;
    float* outscalars = out + (size_t)BB * KK;

    char* ws = (char*)d_ws;
    size_t off = 0;
    float* part    = (float*)(ws + off); off += (size_t)MAXITEMS * DD * DD * 4; // 16 MB
    float* emp     = (float*)(ws + off); off += KK * DD * 4;                    // 32 KB
    int*   sorted  = (int*)  (ws + off); off += BB * 4;                         // 64 KB
    int*   assign  = (int*)  (ws + off); off += BB * 4;                         // 64 KB
    int*   bhist   = (int*)  (ws + off); off += 256 * KK * 4;                   // 64 KB
    int4*  items   = (int4*) (ws + off); off += MAXITEMS * 16;
    float* cw      = (float*)(ws + off); off += 256;
    int*   itemcnt = (int*)  (ws + off); off += 256;
    int*   ist     = (int*)  (ws + off); off += 256;
    int*   ien     = (int*)  (ws + off); off += 256;

    k_rows    <<<256, 256, 0, stream>>>(x, centers, out, assign, bhist,
                                        outscalars, emp);
    k_scat    <<<256, 256, 0, stream>>>(assign, bhist, sorted, cw, items,
                                        itemcnt, ist, ien);
    k_seg     <<<MAXITEMS, 256, 0, stream>>>(x, sorted, items, itemcnt, part, emp);
    k_redfinal<<<KK * 8, 256, 0, stream>>>(part, emp, cw, centers, ist, ien,
                                           outscalars);
}